// Round 15
// baseline (4692.957 us; speedup 1.0000x reference)
//
#include <hip/hip_runtime.h>
#include <cstddef>
#include <cstdint>

#define NB     8
#define L_SEQ  513
#define DMODEL 768
#define EDIM   1536
#define XZDIM  3072
#define NSTATE 16
#define DBCW   80
#define RDIM   48
#define ROWS   (NB*L_SEQ)        /* 4104 */
#define RE     ((size_t)ROWS*EDIM)
#define KSPLIT_DBC 8

typedef unsigned short u16;
typedef __bf16 bf16x8 __attribute__((ext_vector_type(8)));
typedef float  f32x4  __attribute__((ext_vector_type(4)));

__device__ __forceinline__ u16 f2b(float f) {      // RNE float->bf16
  uint32_t x = __float_as_uint(f);
  uint32_t r = x + 0x7fffu + ((x >> 16) & 1u);
  return (u16)(r >> 16);
}

// async global(16B/lane) -> LDS (wave-uniform base + lane*16)
__device__ __forceinline__ void glds16(const void* g, void* l) {
  __builtin_amdgcn_global_load_lds(
      (const __attribute__((address_space(1))) uint32_t*)g,
      (__attribute__((address_space(3))) uint32_t*)l, 16, 0, 0);
}

// ---------------------------------------------------------------- fp32 -> bf16 converters
__global__ __launch_bounds__(256) void f2b_k(const float* __restrict__ in,
                                             u16* __restrict__ out, int n)
{
  int i = (blockIdx.x*256 + threadIdx.x) * 4;
  if (i >= n) return;
  float4 v = *reinterpret_cast<const float4*>(in + i);
  ushort4 o;
  o.x = f2b(v.x); o.y = f2b(v.y); o.z = f2b(v.z); o.w = f2b(v.w);
  *reinterpret_cast<ushort4*>(out + i) = o;
}

__global__ __launch_bounds__(256) void f2b2_k(const float* __restrict__ a,
                                              const float* __restrict__ b,
                                              u16* __restrict__ oa,
                                              u16* __restrict__ ob,
                                              int n1, int n2)
{
  int i = (blockIdx.x*256 + threadIdx.x) * 4;
  if (i < n1) {
    float4 v = *reinterpret_cast<const float4*>(a + i);
    ushort4 o; o.x=f2b(v.x); o.y=f2b(v.y); o.z=f2b(v.z); o.w=f2b(v.w);
    *reinterpret_cast<ushort4*>(oa + i) = o;
  } else {
    int j = i - n1;
    if (j < n2) {
      float4 v = *reinterpret_cast<const float4*>(b + j);
      ushort4 o; o.x=f2b(v.x); o.y=f2b(v.y); o.z=f2b(v.z); o.w=f2b(v.w);
      *reinterpret_cast<ushort4*>(ob + j) = o;
    }
  }
}

// dt_proj weights [nrows][48] f32 -> [nrows][64] bf16, cols 48..63 zero
__global__ __launch_bounds__(256) void cvt_dtw_k(const float* __restrict__ in,
                                                 u16* __restrict__ out, int nrows)
{
  int idx = blockIdx.x*256 + threadIdx.x;
  if (idx >= nrows*16) return;
  int row = idx >> 4, c4 = (idx & 15) * 4;
  ushort4 o; o.x = o.y = o.z = o.w = 0;
  if (c4 < RDIM) {
    float4 v = *reinterpret_cast<const float4*>(in + (size_t)row*RDIM + c4);
    o.x = f2b(v.x); o.y = f2b(v.y); o.z = f2b(v.z); o.w = f2b(v.w);
  }
  *reinterpret_cast<ushort4*>(out + (size_t)row*64 + c4) = o;
}

// ---------------------------------------------------------------- im2col for patch embed (bf16 out)
__global__ __launch_bounds__(256) void im2col_k(const float* __restrict__ x,
                                                u16* __restrict__ P)
{
  int idx = blockIdx.x*256 + threadIdx.x;      // 4096*64
  int col4 = (idx & 63) * 4;
  int r = idx >> 6;
  int b = r >> 9, p = r & 511;
  int ph = p >> 6, pcol = p & 63;
  int i = col4 >> 4, j = col4 & 15;
  const float* src = x + (size_t)b*131072 + (size_t)(ph*16 + i)*1024 + pcol*16 + j;
  float4 v = *reinterpret_cast<const float4*>(src);
  ushort4 o;
  o.x = f2b(v.x); o.y = f2b(v.y); o.z = f2b(v.z); o.w = f2b(v.w);
  *reinterpret_cast<ushort4*>(P + (size_t)r*256 + col4) = o;
}

// ---------------------------------------------------------------- insert tokens + CLS into h
__global__ __launch_bounds__(256) void insert_k(const float* __restrict__ tokf,
                                                const float* __restrict__ cls,
                                                float* __restrict__ h)
{
  int idx = blockIdx.x*256 + threadIdx.x;      // 4104*192
  if (idx >= ROWS*192) return;
  int d4 = (idx % 192) * 4;
  int row = idx / 192;
  int b = row / L_SEQ, l = row - b*L_SEQ;
  float4 v;
  if (l == 256) v = *reinterpret_cast<const float4*>(cls + d4);
  else {
    int p = (l < 256) ? l : l - 1;
    v = *reinterpret_cast<const float4*>(tokf + ((size_t)(b*512 + p))*DMODEL + d4);
  }
  *reinterpret_cast<float4*>(h + (size_t)row*DMODEL + d4) = v;
}

// ---------------------------------------------------------------- layernorm (768) -> bf16 out
__device__ __forceinline__ void wave_reduce2(float& s, float& ss) {
  #pragma unroll
  for (int o = 32; o; o >>= 1) { s += __shfl_down(s, o); ss += __shfl_down(ss, o); }
}

__global__ __launch_bounds__(256) void layernorm_k(
    const float* __restrict__ x, const float* __restrict__ w,
    const float* __restrict__ b, u16* __restrict__ y)
{
  int row = blockIdx.x;
  const float* xr = x + (size_t)row*DMODEL;
  u16*         yr = y + (size_t)row*DMODEL;
  int t = threadIdx.x;
  float v0 = xr[t], v1 = xr[t+256], v2 = xr[t+512];
  float s = v0+v1+v2, ss = v0*v0 + v1*v1 + v2*v2;
  wave_reduce2(s, ss);
  __shared__ float sm[8];
  if ((t & 63) == 0) { sm[t>>6] = s; sm[4 + (t>>6)] = ss; }
  __syncthreads();
  s  = sm[0]+sm[1]+sm[2]+sm[3];
  ss = sm[4]+sm[5]+sm[6]+sm[7];
  float mean = s * (1.f/768.f);
  float var  = ss * (1.f/768.f) - mean*mean;
  float rstd = rsqrtf(var + 1e-5f);
  yr[t]     = f2b((v0-mean)*rstd*w[t]     + b[t]);
  yr[t+256] = f2b((v1-mean)*rstd*w[t+256] + b[t+256]);
  yr[t+512] = f2b((v2-mean)*rstd*w[t+512] + b[t+512]);
}

// ---------------------------------------------------------------- bf16 MFMA GEMM (double-buffered, counted vmcnt)
// C = A(MxK) * W(NxK)^T.  Tile 128x128, BK=32, 4 waves, 2-phase pipeline.
// XCD-aware bijective swizzle of the flattened 2D tile index (m204 formula):
// each XCD gets a contiguous chunk of tile-space -> W-panel reads hit XCD L2.
// gridDim.z = ndir * zsplit; dir = z / zsplit applies batch strides;
// kslab = z % zsplit splits K (partials at C + kslab*M*ldc; epilogue 0 only).
// epilogue: 0 = store, 1 = C += acc, 2 = softplus(acc+bias[n]), 3 = acc + bias[n]
__global__ __launch_bounds__(256) void gemm_bf16_k(
    const u16* __restrict__ A, int lda,
    const u16* __restrict__ W, int ldw,
    float* __restrict__ C, int ldc, int M, int Ncols, int K,
    const float* __restrict__ bias, int epilogue,
    int zsplit, size_t bsA, size_t bsW, size_t bsC, size_t bsBias)
{
  __shared__ __align__(16) u16 Asl[2][4096];
  __shared__ __align__(16) u16 Wsl[2][4096];
  const int tid = threadIdx.x;

  // ---- XCD swizzle (bijective for any nwg)
  int nbx  = (int)gridDim.x;
  int nwg  = nbx * (int)gridDim.y;
  int orig = (int)blockIdx.y * nbx + (int)blockIdx.x;
  int qs = nwg >> 3, rs = nwg & 7, xcd = orig & 7, off = orig >> 3;
  int wg = (xcd < rs ? xcd*(qs+1) : rs*(qs+1) + (xcd-rs)*qs) + off;
  const int bm = (wg / nbx) << 7, bn = (wg % nbx) << 7;

  const int wv = tid >> 6, ln = tid & 63;
  const int wr = (wv >> 1) << 6, wc = (wv & 1) << 6;

  int kb = 0, ke = K;
  {
    int zb = (int)blockIdx.z;
    int dir = zb / zsplit, kslab = zb - dir*zsplit;
    A += (size_t)dir * bsA;
    W += (size_t)dir * bsW;
    C += (size_t)dir * bsC;
    if (bias) bias += (size_t)dir * bsBias;
    if (zsplit > 1) {
      int ksl = K / zsplit;
      kb = kslab * ksl; ke = kb + ksl;
      C += (size_t)kslab * (size_t)M * (size_t)ldc;
    }
  }

  const int q0 = (ln >> 4) * 8;
  const int r0 = wv*16 + (ln & 15);
  const int r1 = (wv+4)*16 + (ln & 15);

  int ar0 = bm + r0; if (ar0 >= M) ar0 = M-1;
  int ar1 = bm + r1; if (ar1 >= M) ar1 = M-1;
  int nr0 = bn + r0; if (nr0 >= Ncols) nr0 = Ncols-1;
  int nr1 = bn + r1; if (nr1 >= Ncols) nr1 = Ncols-1;
  const u16* A0 = A + (size_t)ar0*lda + q0;
  const u16* A1 = A + (size_t)ar1*lda + q0;
  const u16* W0 = W + (size_t)nr0*ldw + q0;
  const u16* W1 = W + (size_t)nr1*ldw + q0;

  auto STAGE = [&](int buf, int k0) {
    char* ab = (char*)&Asl[buf][0];
    char* wb = (char*)&Wsl[buf][0];
    glds16(A0 + k0, ab + wv*1024);
    glds16(A1 + k0, ab + 4096 + wv*1024);
    glds16(W0 + k0, wb + wv*1024);
    glds16(W1 + k0, wb + 4096 + wv*1024);
  };

  f32x4 acc[4][4];
  #pragma unroll
  for (int m = 0; m < 4; ++m)
    #pragma unroll
    for (int n = 0; n < 4; ++n) acc[m][n] = (f32x4){0.f,0.f,0.f,0.f};

  const int niter = (ke - kb) >> 5;
  STAGE(0, kb);
  for (int it = 0; it < niter; ++it) {
    const int p = it & 1;
    if (it + 1 < niter) {
      STAGE(p ^ 1, kb + (it + 1) * 32);
      asm volatile("s_waitcnt vmcnt(4)" ::: "memory");
    } else {
      asm volatile("s_waitcnt vmcnt(0)" ::: "memory");
    }
    __builtin_amdgcn_s_barrier();
    bf16x8 fa[4], fb[4];
    #pragma unroll
    for (int m = 0; m < 4; ++m)
      fa[m] = *reinterpret_cast<const bf16x8*>(&Asl[p][((wr>>4)+m)*512 + ln*8]);
    #pragma unroll
    for (int n = 0; n < 4; ++n)
      fb[n] = *reinterpret_cast<const bf16x8*>(&Wsl[p][((wc>>4)+n)*512 + ln*8]);
    #pragma unroll
    for (int m = 0; m < 4; ++m)
      #pragma unroll
      for (int n = 0; n < 4; ++n)
        acc[m][n] = __builtin_amdgcn_mfma_f32_16x16x32_bf16(fa[m], fb[n], acc[m][n], 0, 0, 0);
    __builtin_amdgcn_s_barrier();
  }

  const int crow0 = bm + wr + ((ln >> 4) << 2);
  const int ccol0 = bn + wc + (ln & 15);
  #pragma unroll
  for (int m = 0; m < 4; ++m) {
    #pragma unroll
    for (int q = 0; q < 4; ++q) {
      int row = crow0 + m*16 + q;
      if (row >= M) continue;
      float* Cr = C + (size_t)row*ldc;
      #pragma unroll
      for (int n = 0; n < 4; ++n) {
        int col = ccol0 + n*16;
        if (col >= Ncols) continue;
        float v = acc[m][n][q];
        if (epilogue == 1) v += Cr[col];
        else if (epilogue == 2) {
          v += bias[col];
          v = fmaxf(v, 0.f) + log1pf(__expf(-fabsf(v)));   // softplus
        } else if (epilogue == 3) v += bias[col];
        Cr[col] = v;
      }
    }
  }
}

// ---------------------------------------------------------------- reduce K-split slabs (both dirs) -> dbc f32 + dt bf16 (padded 64)
__global__ void reduce_split2_k(const float* __restrict__ part,
                                float* __restrict__ dbc2, u16* __restrict__ dt48,
                                int nsplit)
{
  int i = blockIdx.x * 256 + threadIdx.x;
  if (i >= 2*ROWS*DBCW) return;
  int dir = i / (ROWS*DBCW);
  int j   = i - dir*(ROWS*DBCW);
  const float* p = part + (size_t)dir*nsplit*(ROWS*DBCW);
  float s = 0.f;
  for (int z = 0; z < nsplit; ++z) s += p[(size_t)z*(ROWS*DBCW) + j];
  dbc2[i] = s;
  int row = j / DBCW, col = j - row*DBCW;
  if (col < RDIM)    dt48[(size_t)dir*ROWS*64 + (size_t)row*64 + col] = f2b(s);
  else if (col < 64) dt48[(size_t)dir*ROWS*64 + (size_t)row*64 + col] = 0;
}

// ---------------------------------------------------------------- fused: sum 4 out_proj K-slabs + residual add into h + next-layer LN -> bf16
__global__ __launch_bounds__(256) void reduce4_ln_k(
    const float* __restrict__ part, float* __restrict__ h,
    const float* __restrict__ w, const float* __restrict__ b,
    u16* __restrict__ y)
{
  int row = blockIdx.x;
  int t = threadIdx.x;
  const size_t S = (size_t)ROWS*DMODEL;
  const size_t base = (size_t)row*DMODEL;
  float v[3];
  #pragma unroll
  for (int j = 0; j < 3; ++j) {
    size_t idx = base + t + j*256;
    float s = (part[idx] + part[S+idx]) + (part[2*S+idx] + part[3*S+idx]);
    s += h[idx];
    h[idx] = s;
    v[j] = s;
  }
  if (!w) return;                 // last layer: no LN needed here
  float s = v[0]+v[1]+v[2], ss = v[0]*v[0]+v[1]*v[1]+v[2]*v[2];
  wave_reduce2(s, ss);
  __shared__ float sm[8];
  if ((t & 63) == 0) { sm[t>>6] = s; sm[4+(t>>6)] = ss; }
  __syncthreads();
  s = sm[0]+sm[1]+sm[2]+sm[3]; ss = sm[4]+sm[5]+sm[6]+sm[7];
  float mean = s*(1.f/768.f);
  float var  = ss*(1.f/768.f) - mean*mean;
  float rstd = rsqrtf(var + 1e-5f);
  u16* yr = y + base;
  #pragma unroll
  for (int j = 0; j < 3; ++j) {
    int col = t + j*256;
    yr[col] = f2b((v[j]-mean)*rstd*w[col] + b[col]);
  }
}

// ---------------------------------------------------------------- depthwise causal conv (K=4) + SiLU, both dirs, bf16 out
__global__ __launch_bounds__(256) void dwconv_silu_k(
    const float* __restrict__ xz,
    const float* __restrict__ w_f, const float* __restrict__ w_b,
    const float* __restrict__ b_f, const float* __restrict__ b_b,
    u16* __restrict__ outb2)
{
  const int dir = blockIdx.y;
  const float* w    = dir ? w_b : w_f;
  const float* bias = dir ? b_b : b_f;
  u16* outb = outb2 + (size_t)dir*RE;
  int idx = blockIdx.x * 256 + threadIdx.x;          // ROWS * EDIM/4
  int r = idx / (EDIM/4);
  int e4 = (idx - r*(EDIM/4)) * 4;
  int b = r / L_SEQ, t = r - b*L_SEQ;
  float4 acc = *reinterpret_cast<const float4*>(&bias[e4]);
  float4 wq0 = *reinterpret_cast<const float4*>(&w[(size_t)(e4+0)*4]);
  float4 wq1 = *reinterpret_cast<const float4*>(&w[(size_t)(e4+1)*4]);
  float4 wq2 = *reinterpret_cast<const float4*>(&w[(size_t)(e4+2)*4]);
  float4 wq3 = *reinterpret_cast<const float4*>(&w[(size_t)(e4+3)*4]);
  #pragma unroll
  for (int k = 0; k < 4; ++k) {
    int tt = t - 3 + k;
    if (tt >= 0) {
      int phys = dir ? (L_SEQ-1 - tt) : tt;
      float4 xv = *reinterpret_cast<const float4*>(
          &xz[((size_t)b*L_SEQ + phys)*XZDIM + e4]);
      float w0 = (k==0)?wq0.x:(k==1)?wq0.y:(k==2)?wq0.z:wq0.w;
      float w1 = (k==0)?wq1.x:(k==1)?wq1.y:(k==2)?wq1.z:wq1.w;
      float w2 = (k==0)?wq2.x:(k==1)?wq2.y:(k==2)?wq2.z:wq2.w;
      float w3 = (k==0)?wq3.x:(k==1)?wq3.y:(k==2)?wq3.z:wq3.w;
      acc.x = fmaf(xv.x, w0, acc.x);
      acc.y = fmaf(xv.y, w1, acc.y);
      acc.z = fmaf(xv.z, w2, acc.z);
      acc.w = fmaf(xv.w, w3, acc.w);
    }
  }
  float4 sv;
  sv.x = acc.x / (1.f + __expf(-acc.x));
  sv.y = acc.y / (1.f + __expf(-acc.y));
  sv.z = acc.z / (1.f + __expf(-acc.z));
  sv.w = acc.w / (1.f + __expf(-acc.w));
  ushort4 ob;
  ob.x = f2b(sv.x); ob.y = f2b(sv.y); ob.z = f2b(sv.z); ob.w = f2b(sv.w);
  *reinterpret_cast<ushort4*>(&outb[(size_t)r*EDIM + e4]) = ob;
}

// ---------------------------------------------------------------- SSM scan (both dirs, chunked LDS, packed-du, DPP reduce)
// yb[s][g] already includes the D-term (yp + u*D) -- writeout only gates with silu(z).
__device__ __forceinline__ float dpp_reduce16(float v) {
  v += __int_as_float(__builtin_amdgcn_update_dpp(0, __float_as_int(v), 0x111, 0xf, 0xf, true));
  v += __int_as_float(__builtin_amdgcn_update_dpp(0, __float_as_int(v), 0x112, 0xf, 0xf, true));
  v += __int_as_float(__builtin_amdgcn_update_dpp(0, __float_as_int(v), 0x114, 0xf, 0xf, true));
  v += __int_as_float(__builtin_amdgcn_update_dpp(0, __float_as_int(v), 0x118, 0xf, 0xf, true));
  return v;   // lane 15 of each 16-lane row holds the sum
}

#define TC 32
#define NCH ((L_SEQ + TC - 1) / TC)   /* 17 */

__global__ __launch_bounds__(256) void ssm_scan_k(
    const float* __restrict__ delta2, const u16* __restrict__ ub2,
    const float* __restrict__ dbc2,
    const float* __restrict__ Alf, const float* __restrict__ Alb,
    const float* __restrict__ Dpf, const float* __restrict__ Dpb,
    const float* __restrict__ xz,  u16* __restrict__ yhalf)
{
  __shared__ __align__(16) float du[2][TC][16][2];   // [d,u] interleaved -> 1 b64 read/step
  __shared__ __align__(16) float Bs[2][16][TC+4];
  __shared__ __align__(16) float Cs[2][16][TC+4];
  __shared__ __align__(16) float yb[TC][16];

  const int dir = blockIdx.z;
  const float* delta = delta2 + (size_t)dir*RE;
  const u16*   ub    = ub2    + (size_t)dir*RE;
  const float* dbc   = dbc2   + (size_t)dir*ROWS*DBCW;
  const float* A_log = dir ? Alb : Alf;
  const float* Dp    = dir ? Dpb : Dpf;
  u16* yh = yhalf + (size_t)dir*RE;

  const int tid = threadIdx.x;
  const int g = tid >> 4, n = tid & 15;
  const int b = blockIdx.y;
  const int e0 = blockIdx.x * 16;
  const int e = e0 + g;
  const size_t rb = (size_t)b * L_SEQ;

  const float a  = -__expf(A_log[(size_t)e*NSTATE + n]);
  const float dp = Dp[e];

  const int ss_ = tid >> 3;          // 0..31 : step within chunk
  const int c2  = (tid & 7) * 2;     // 0..14 : e-pair
  const int j4  = (tid & 7) * 4;     // 0..28 : quad within 32 B/C floats

  float2 dv = make_float2(0,0);
  uint32_t uv = 0;
  float4 bcv = make_float4(0,0,0,0);

  auto LOAD = [&](int c) {
    int Tn = min(TC, L_SEQ - c*TC);
    if (ss_ < Tn) {
      size_t r = rb + c*TC + ss_;
      dv  = *reinterpret_cast<const float2*>(&delta[r*EDIM + e0 + c2]);
      uv  = *reinterpret_cast<const uint32_t*>(&ub[r*EDIM + e0 + c2]);
      bcv = *reinterpret_cast<const float4*>(&dbc[r*DBCW + RDIM + j4]);
    }
  };
  auto STORE = [&](int p, int c) {
    int Tn = min(TC, L_SEQ - c*TC);
    if (ss_ < Tn) {
      float2 w0 = make_float2(dv.x, __uint_as_float((uv & 0xffffu) << 16));
      float2 w1 = make_float2(dv.y, __uint_as_float(uv & 0xffff0000u));
      *reinterpret_cast<float2*>(&du[p][ss_][c2][0])   = w0;
      *reinterpret_cast<float2*>(&du[p][ss_][c2+1][0]) = w1;
      if (j4 < 16) {
        Bs[p][j4  ][ss_] = bcv.x; Bs[p][j4+1][ss_] = bcv.y;
        Bs[p][j4+2][ss_] = bcv.z; Bs[p][j4+3][ss_] = bcv.w;
      } else {
        Cs[p][j4-16][ss_] = bcv.x; Cs[p][j4-15][ss_] = bcv.y;
        Cs[p][j4-14][ss_] = bcv.z; Cs[p][j4-13][ss_] = bcv.w;
      }
    }
  };

  float hst = 0.f;
  LOAD(0);
  STORE(0, 0);
  __syncthreads();

  int p = 0;
  for (int c = 0; c < NCH; ++c) {
    const int t0 = c * TC;
    const int T  = min(TC, L_SEQ - t0);
    if (c + 1 < NCH) LOAD(c + 1);

    int s = 0;
    for (; s + 3 < T; s += 4) {
      float4 Bv = *reinterpret_cast<const float4*>(&Bs[p][n][s]);
      float4 Cv = *reinterpret_cast<const float4*>(&Cs[p][n][s]);
      #pragma unroll
      for (int i = 0; i < 4; ++i) {
        float Bt = (i==0)?Bv.x:(i==1)?Bv.y:(i==2)?Bv.z:Bv.w;
        float Ct = (i==0)?Cv.x:(i==1)?Cv.y:(i==2)?Cv.z:Cv.w;
        float2 duv = *reinterpret_cast<const float2*>(&du[p][s+i][g][0]);
        float d  = duv.x;
        float uu = duv.y;
        hst = fmaf(hst, __expf(d*a), d*uu*Bt);
        float yp = dpp_reduce16(hst * Ct);
        if (n == 15) yb[s+i][g] = yp + uu*dp;
      }
    }
    for (; s < T; ++s) {
      float Bt = Bs[p][n][s], Ct = Cs[p][n][s];
      float2 duv = *reinterpret_cast<const float2*>(&du[p][s][g][0]);
      float d  = duv.x;
      float uu = duv.y;
      hst = fmaf(hst, __expf(d*a), d*uu*Bt);
      float yp = dpp_reduce16(hst * Ct);
      if (n == 15) yb[s][g] = yp + uu*dp;
    }
    __syncthreads();

    // writeout: yb already includes D-term; just gate with silu(z) and store bf16
    if (ss_ < T) {
      int t = t0 + ss_;
      int phys = dir ? (L_SEQ-1 - t) : t;
      size_t pr = rb + phys;
      float2 yv = *reinterpret_cast<const float2*>(&yb[ss_][c2]);
      float2 zv = *reinterpret_cast<const float2*>(&xz[pr*XZDIM + EDIM + e0 + c2]);
      ushort2 o;
      o.x = f2b(yv.x * (zv.x / (1.f + __expf(-zv.x))));
      o.y = f2b(yv.y * (zv.y / (1.f + __expf(-zv.y))));
      *reinterpret_cast<ushort2*>(&yh[pr*EDIM + e0 + c2]) = o;
    }
    if (c + 1 < NCH) STORE(p ^ 1, c + 1);
    __syncthreads();
    p ^= 1;
  }
}

// ---------------------------------------------------------------- yf + yb -> bf16 (8-wide)
__global__ __launch_bounds__(256) void add_ybf_k(const u16* __restrict__ yhalf,
                                                 u16* __restrict__ ybf)
{
  size_t i = ((size_t)blockIdx.x*256 + threadIdx.x) * 8;
  uint4 a = *reinterpret_cast<const uint4*>(yhalf + i);
  uint4 b = *reinterpret_cast<const uint4*>(yhalf + RE + i);
  uint32_t av[4] = {a.x, a.y, a.z, a.w};
  uint32_t bv[4] = {b.x, b.y, b.z, b.w};
  uint32_t ov[4];
  #pragma unroll
  for (int q = 0; q < 4; ++q) {
    float lo = __uint_as_float((av[q] & 0xffffu) << 16) +
               __uint_as_float((bv[q] & 0xffffu) << 16);
    float hi = __uint_as_float(av[q] & 0xffff0000u) +
               __uint_as_float(bv[q] & 0xffff0000u);
    ov[q] = (uint32_t)f2b(lo) | ((uint32_t)f2b(hi) << 16);
  }
  uint4 o = {ov[0], ov[1], ov[2], ov[3]};
  *reinterpret_cast<uint4*>(ybf + i) = o;
}

// ---------------------------------------------------------------- head
__global__ __launch_bounds__(256) void head_k(
    const float* __restrict__ h,
    const float* __restrict__ fnw, const float* __restrict__ fnb,
    const float* __restrict__ hnw, const float* __restrict__ hnb,
    const float* __restrict__ hw,  const float* __restrict__ hb,
    float* __restrict__ out)
{
  int b = blockIdx.x, t = threadIdx.x;
  const float* xr = h + ((size_t)b*L_SEQ + 256)*DMODEL;
  __shared__ float feat[DMODEL];
  __shared__ float sm[8];
  float v0 = xr[t], v1 = xr[t+256], v2 = xr[t+512];
  float s = v0+v1+v2, ss = v0*v0+v1*v1+v2*v2;
  wave_reduce2(s, ss);
  if ((t & 63) == 0) { sm[t>>6] = s; sm[4+(t>>6)] = ss; }
  __syncthreads();
  s = sm[0]+sm[1]+sm[2]+sm[3]; ss = sm[4]+sm[5]+sm[6]+sm[7];
  float mean = s*(1.f/768.f), var = ss*(1.f/768.f) - mean*mean;
  float rstd = rsqrtf(var + 1e-5f);
  float f0 = (v0-mean)*rstd*fnw[t]     + fnb[t];
  float f1 = (v1-mean)*rstd*fnw[t+256] + fnb[t+256];
  float f2 = (v2-mean)*rstd*fnw[t+512] + fnb[t+512];
  s = f0+f1+f2; ss = f0*f0+f1*f1+f2*f2;
  wave_reduce2(s, ss);
  __syncthreads();
  if ((t & 63) == 0) { sm[t>>6] = s; sm[4+(t>>6)] = ss; }
  __syncthreads();
  s = sm[0]+sm[1]+sm[2]+sm[3]; ss = sm[4]+sm[5]+sm[6]+sm[7];
  mean = s*(1.f/768.f); var = ss*(1.f/768.f) - mean*mean;
  rstd = rsqrtf(var + 1e-5f);
  feat[t]     = (f0-mean)*rstd*hnw[t]     + hnb[t];
  feat[t+256] = (f1-mean)*rstd*hnw[t+256] + hnb[t+256];
  feat[t+512] = (f2-mean)*rstd*hnw[t+512] + hnb[t+512];
  __syncthreads();
  for (int c = 0; c < 10; ++c) {
    float d = 0.f;
    for (int i = t; i < DMODEL; i += 256) d = fmaf(feat[i], hw[(size_t)c*DMODEL + i], d);
    #pragma unroll
    for (int o = 32; o; o >>= 1) d += __shfl_down(d, o);
    __syncthreads();
    if ((t & 63) == 0) sm[t>>6] = d;
    __syncthreads();
    if (t == 0) out[b*10 + c] = sm[0]+sm[1]+sm[2]+sm[3] + hb[c];
  }
}

// ================================================================ launch
extern "C" void kernel_launch(void* const* d_in, const int* in_sizes, int n_in,
                              void* d_out, int out_size, void* d_ws, size_t ws_size,
                              hipStream_t stream)
{
  (void)in_sizes; (void)n_in; (void)out_size; (void)ws_size;
  const float* x           = (const float*)d_in[0];
  const float* patch_w     = (const float*)d_in[1];
  const float* patch_b     = (const float*)d_in[2];
  const float* cls_tok     = (const float*)d_in[3];
  const float* norm_w      = (const float*)d_in[4];
  const float* norm_b      = (const float*)d_in[5];
  const float* in_proj_w   = (const float*)d_in[6];
  const float* conv_w_f    = (const float*)d_in[7];
  const float* conv_b_f    = (const float*)d_in[8];
  const float* x_proj_w_f  = (const float*)d_in[9];
  const float* dt_proj_w_f = (const float*)d_in[10];
  const float* dt_proj_b_f = (const float*)d_in[11];
  const float* A_log_f     = (const float*)d_in[12];
  const float* D_f         = (const float*)d_in[13];
  const float* conv_w_b    = (const float*)d_in[14];
  const float* conv_b_b    = (const float*)d_in[15];
  const float* x_proj_w_b  = (const float*)d_in[16];
  const float* dt_proj_w_b = (const float*)d_in[17];
  const float* dt_proj_b_b = (const float*)d_in[18];
  const float* A_log_b     = (const float*)d_in[19];
  const float* D_b         = (const float*)d_in[20];
  const float* out_proj_w  = (const float*)d_in[21];
  const float* fnorm_w     = (const float*)d_in[22];
  const float* fnorm_b     = (const float*)d_in[23];
  const float* head_norm_w = (const float*)d_in[24];
  const float* head_norm_b = (const float*)d_in[25];
  const float* head_w      = (const float*)d_in[26];
  const float* head_b      = (const float*)d_in[27];
  float* out = (float*)d_out;

  // workspace layout (float units) — base ~172 MB
  float* ws = (float*)d_ws;
  float* h      = ws;        ws += (size_t)ROWS*DMODEL;
  u16*   hn     = (u16*)ws;  ws += RE/2;                  // [ROWS][1536] bf16 region
  u16*   ybf    = hn;                                     // alias: hn consumed by in_proj before add_ybf writes
  float* xz     = ws;        ws += (size_t)ROWS*XZDIM;
  u16*   ubufb2 = (u16*)ws;  ws += RE;                    // [2][ROWS][EDIM] bf16
  float* dbc2   = ws;        ws += (size_t)2*ROWS*DBCW;
  u16*   dt48b2 = (u16*)ws;  ws += (size_t)2*ROWS*64/2;
  float* delta2 = ws;        ws += 2*RE;                  // [2][ROWS][EDIM] f32
  u16*   yhalf  = (u16*)ws;  ws += RE;                    // [2][ROWS][EDIM] bf16
  u16*   wbf_a  = (u16*)ws;  ws += (size_t)XZDIM*DMODEL/2;
  u16*   wbf_b  = (u16*)ws;  ws += (size_t)DMODEL*EDIM/2;
  u16*   pwbf   = (u16*)ws;  ws += (size_t)DMODEL*256/2;
  u16*   xwbf   = (u16*)ws;  ws += (size_t)2*12*DBCW*EDIM/2;  // [2][12][80][1536]
  u16*   dtwbf  = (u16*)ws;  ws += (size_t)2*12*EDIM*64/2;    // [2][12][1536][64]
  float* dtb2   = ws;        ws += (size_t)2*12*EDIM;
  float* dbcp   = delta2;          // x_proj partials alias (21 MB <= 50 MB, pre-dt_proj)
  float* opart  = delta2;          // out_proj partials alias (4 slabs x 12.6 MB = 50.4 MB, post-scan)
  u16*   Pim    = ubufb2;          // patch-phase alias
  float* tokf   = delta2;          // patch-phase alias

  // ---- one-time weight conversions
  f2b_k<<<(DMODEL*256)/1024, 256, 0, stream>>>(patch_w, pwbf, DMODEL*256);
  f2b_k<<<(12*DBCW*EDIM)/1024, 256, 0, stream>>>(x_proj_w_f, xwbf, 12*DBCW*EDIM);
  f2b_k<<<(12*DBCW*EDIM)/1024, 256, 0, stream>>>(x_proj_w_b, xwbf + (size_t)12*DBCW*EDIM, 12*DBCW*EDIM);
  cvt_dtw_k<<<(12*EDIM*16)/256, 256, 0, stream>>>(dt_proj_w_f, dtwbf, 12*EDIM);
  cvt_dtw_k<<<(12*EDIM*16)/256, 256, 0, stream>>>(dt_proj_w_b, dtwbf + (size_t)12*EDIM*64, 12*EDIM);
  hipMemcpyAsync(dtb2,           dt_proj_b_f, (size_t)12*EDIM*4, hipMemcpyDeviceToDevice, stream);
  hipMemcpyAsync(dtb2 + 12*EDIM, dt_proj_b_b, (size_t)12*EDIM*4, hipMemcpyDeviceToDevice, stream);

  // ---- patch embed as GEMM
  im2col_k<<<(4096*64)/256, 256, 0, stream>>>(x, Pim);
  {
    dim3 g(DMODEL/128, 4096/128);
    gemm_bf16_k<<<g, 256, 0, stream>>>(Pim, 256, pwbf, 256, tokf, DMODEL,
                                       4096, DMODEL, 256, patch_b, 3,
                                       1, 0, 0, 0, 0);
  }
  insert_k<<<(ROWS*192 + 255)/256, 256, 0, stream>>>(tokf, cls_tok, h);

  const int MT = (ROWS + 127)/128;   // 33

  // layer-0 LN (subsequent LNs fused into reduce4_ln_k)
  layernorm_k<<<ROWS, 256, 0, stream>>>(h, norm_w, norm_b, hn);

  for (int i = 0; i < 12; ++i) {
    f2b2_k<<<(XZDIM*DMODEL + DMODEL*EDIM)/1024, 256, 0, stream>>>(
        in_proj_w + (size_t)i*XZDIM*DMODEL, out_proj_w + (size_t)i*DMODEL*EDIM,
        wbf_a, wbf_b, XZDIM*DMODEL, DMODEL*EDIM);
    {   // in_proj (bf16 MFMA)
      dim3 g(XZDIM/128, MT);
      gemm_bf16_k<<<g, 256, 0, stream>>>(hn, DMODEL, wbf_a, DMODEL,
                                         xz, XZDIM, ROWS, XZDIM, DMODEL, nullptr, 0,
                                         1, 0, 0, 0, 0);
    }
    {   // dwconv both dirs
      dim3 g((ROWS*EDIM/4)/256, 2);
      dwconv_silu_k<<<g, 256, 0, stream>>>(xz,
          conv_w_f + (size_t)i*EDIM*4, conv_w_b + (size_t)i*EDIM*4,
          conv_b_f + (size_t)i*EDIM,   conv_b_b + (size_t)i*EDIM, ubufb2);
    }
    {   // x_proj both dirs (K-split 8 each)
      dim3 g(1, MT, 2*KSPLIT_DBC);
      gemm_bf16_k<<<g, 256, 0, stream>>>(ubufb2, EDIM,
          xwbf + (size_t)i*DBCW*EDIM, EDIM,
          dbcp, DBCW, ROWS, DBCW, EDIM, nullptr, 0,
          KSPLIT_DBC, RE, (size_t)12*DBCW*EDIM, (size_t)KSPLIT_DBC*ROWS*DBCW, 0);
      reduce_split2_k<<<(2*ROWS*DBCW + 255)/256, 256, 0, stream>>>(
          dbcp, dbc2, dt48b2, KSPLIT_DBC);
    }
    {   // dt_proj both dirs (K padded 48->64) + bias + softplus
      dim3 g(EDIM/128, MT, 2);
      gemm_bf16_k<<<g, 256, 0, stream>>>(dt48b2, 64,
          dtwbf + (size_t)i*EDIM*64, 64,
          delta2, EDIM, ROWS, EDIM, 64, dtb2 + (size_t)i*EDIM, 2,
          1, (size_t)ROWS*64, (size_t)12*EDIM*64, RE, (size_t)12*EDIM);
    }
    {   // scan both dirs
      dim3 g(EDIM/16, NB, 2);
      ssm_scan_k<<<g, 256, 0, stream>>>(delta2, ubufb2, dbc2,
          A_log_f + (size_t)i*EDIM*NSTATE, A_log_b + (size_t)i*EDIM*NSTATE,
          D_f + (size_t)i*EDIM, D_b + (size_t)i*EDIM, xz, yhalf);
    }
    add_ybf_k<<<(int)(RE/8/256), 256, 0, stream>>>(yhalf, ybf);
    {   // out_proj (bf16 MFMA, K-split 4 into opart)
      dim3 g(DMODEL/128, MT, 4);
      gemm_bf16_k<<<g, 256, 0, stream>>>(ybf, EDIM, wbf_b, EDIM,
                                         opart, DMODEL, ROWS, DMODEL, EDIM, nullptr, 0,
                                         4, 0, 0, 0, 0);
    }
    {   // fused: sum 4 slabs + residual into h + next-layer LN -> hn
      const float* lw = (i < 11) ? (norm_w + (size_t)(i+1)*DMODEL) : nullptr;
      const float* lb = (i < 11) ? (norm_b + (size_t)(i+1)*DMODEL) : nullptr;
      reduce4_ln_k<<<ROWS, 256, 0, stream>>>(opart, h, lw, lb, hn);
    }
  }

  head_k<<<NB, 256, 0, stream>>>(h, fnorm_w, fnorm_b, head_norm_w, head_norm_b,
                                 head_w, head_b, out);
}

// Round 16
// 4392.813 us; speedup vs baseline: 1.0683x; 1.0683x over previous
//
#include <hip/hip_runtime.h>
#include <cstddef>
#include <cstdint>

#define NB     8
#define L_SEQ  513
#define DMODEL 768
#define EDIM   1536
#define XZDIM  3072
#define NSTATE 16
#define DBCW   80
#define RDIM   48
#define ROWS   (NB*L_SEQ)        /* 4104 */
#define RE     ((size_t)ROWS*EDIM)
#define KSPLIT_DBC 8

typedef unsigned short u16;
typedef __bf16 bf16x8 __attribute__((ext_vector_type(8)));
typedef float  f32x4  __attribute__((ext_vector_type(4)));

__device__ __forceinline__ u16 f2b(float f) {      // RNE float->bf16
  uint32_t x = __float_as_uint(f);
  uint32_t r = x + 0x7fffu + ((x >> 16) & 1u);
  return (u16)(r >> 16);
}

// async global(16B/lane) -> LDS (wave-uniform base + lane*16)
__device__ __forceinline__ void glds16(const void* g, void* l) {
  __builtin_amdgcn_global_load_lds(
      (const __attribute__((address_space(1))) uint32_t*)g,
      (__attribute__((address_space(3))) uint32_t*)l, 16, 0, 0);
}

// ---------------------------------------------------------------- fp32 -> bf16 converters
__global__ __launch_bounds__(256) void f2b_k(const float* __restrict__ in,
                                             u16* __restrict__ out, int n)
{
  int i = (blockIdx.x*256 + threadIdx.x) * 4;
  if (i >= n) return;
  float4 v = *reinterpret_cast<const float4*>(in + i);
  ushort4 o;
  o.x = f2b(v.x); o.y = f2b(v.y); o.z = f2b(v.z); o.w = f2b(v.w);
  *reinterpret_cast<ushort4*>(out + i) = o;
}

__global__ __launch_bounds__(256) void f2b2_k(const float* __restrict__ a,
                                              const float* __restrict__ b,
                                              u16* __restrict__ oa,
                                              u16* __restrict__ ob,
                                              int n1, int n2)
{
  int i = (blockIdx.x*256 + threadIdx.x) * 4;
  if (i < n1) {
    float4 v = *reinterpret_cast<const float4*>(a + i);
    ushort4 o; o.x=f2b(v.x); o.y=f2b(v.y); o.z=f2b(v.z); o.w=f2b(v.w);
    *reinterpret_cast<ushort4*>(oa + i) = o;
  } else {
    int j = i - n1;
    if (j < n2) {
      float4 v = *reinterpret_cast<const float4*>(b + j);
      ushort4 o; o.x=f2b(v.x); o.y=f2b(v.y); o.z=f2b(v.z); o.w=f2b(v.w);
      *reinterpret_cast<ushort4*>(ob + j) = o;
    }
  }
}

// dt_proj weights [nrows][48] f32 -> [nrows][64] bf16, cols 48..63 zero
__global__ __launch_bounds__(256) void cvt_dtw_k(const float* __restrict__ in,
                                                 u16* __restrict__ out, int nrows)
{
  int idx = blockIdx.x*256 + threadIdx.x;
  if (idx >= nrows*16) return;
  int row = idx >> 4, c4 = (idx & 15) * 4;
  ushort4 o; o.x = o.y = o.z = o.w = 0;
  if (c4 < RDIM) {
    float4 v = *reinterpret_cast<const float4*>(in + (size_t)row*RDIM + c4);
    o.x = f2b(v.x); o.y = f2b(v.y); o.z = f2b(v.z); o.w = f2b(v.w);
  }
  *reinterpret_cast<ushort4*>(out + (size_t)row*64 + c4) = o;
}

// ---------------------------------------------------------------- im2col for patch embed (bf16 out)
__global__ __launch_bounds__(256) void im2col_k(const float* __restrict__ x,
                                                u16* __restrict__ P)
{
  int idx = blockIdx.x*256 + threadIdx.x;      // 4096*64
  int col4 = (idx & 63) * 4;
  int r = idx >> 6;
  int b = r >> 9, p = r & 511;
  int ph = p >> 6, pcol = p & 63;
  int i = col4 >> 4, j = col4 & 15;
  const float* src = x + (size_t)b*131072 + (size_t)(ph*16 + i)*1024 + pcol*16 + j;
  float4 v = *reinterpret_cast<const float4*>(src);
  ushort4 o;
  o.x = f2b(v.x); o.y = f2b(v.y); o.z = f2b(v.z); o.w = f2b(v.w);
  *reinterpret_cast<ushort4*>(P + (size_t)r*256 + col4) = o;
}

// ---------------------------------------------------------------- insert tokens + CLS into h
__global__ __launch_bounds__(256) void insert_k(const float* __restrict__ tokf,
                                                const float* __restrict__ cls,
                                                float* __restrict__ h)
{
  int idx = blockIdx.x*256 + threadIdx.x;      // 4104*192
  if (idx >= ROWS*192) return;
  int d4 = (idx % 192) * 4;
  int row = idx / 192;
  int b = row / L_SEQ, l = row - b*L_SEQ;
  float4 v;
  if (l == 256) v = *reinterpret_cast<const float4*>(cls + d4);
  else {
    int p = (l < 256) ? l : l - 1;
    v = *reinterpret_cast<const float4*>(tokf + ((size_t)(b*512 + p))*DMODEL + d4);
  }
  *reinterpret_cast<float4*>(h + (size_t)row*DMODEL + d4) = v;
}

// ---------------------------------------------------------------- layernorm (768) -> bf16 out
__device__ __forceinline__ void wave_reduce2(float& s, float& ss) {
  #pragma unroll
  for (int o = 32; o; o >>= 1) { s += __shfl_down(s, o); ss += __shfl_down(ss, o); }
}

__global__ __launch_bounds__(256) void layernorm_k(
    const float* __restrict__ x, const float* __restrict__ w,
    const float* __restrict__ b, u16* __restrict__ y)
{
  int row = blockIdx.x;
  const float* xr = x + (size_t)row*DMODEL;
  u16*         yr = y + (size_t)row*DMODEL;
  int t = threadIdx.x;
  float v0 = xr[t], v1 = xr[t+256], v2 = xr[t+512];
  float s = v0+v1+v2, ss = v0*v0 + v1*v1 + v2*v2;
  wave_reduce2(s, ss);
  __shared__ float sm[8];
  if ((t & 63) == 0) { sm[t>>6] = s; sm[4 + (t>>6)] = ss; }
  __syncthreads();
  s  = sm[0]+sm[1]+sm[2]+sm[3];
  ss = sm[4]+sm[5]+sm[6]+sm[7];
  float mean = s * (1.f/768.f);
  float var  = ss * (1.f/768.f) - mean*mean;
  float rstd = rsqrtf(var + 1e-5f);
  yr[t]     = f2b((v0-mean)*rstd*w[t]     + b[t]);
  yr[t+256] = f2b((v1-mean)*rstd*w[t+256] + b[t+256]);
  yr[t+512] = f2b((v2-mean)*rstd*w[t+512] + b[t+512]);
}

// ---------------------------------------------------------------- bf16 MFMA GEMM (double-buffered, counted vmcnt)
// C = A(MxK) * W(NxK)^T.  Tile 128x128, BK=32, 4 waves, 2-phase pipeline.
// gridDim.z = ndir * zsplit; dir = z / zsplit applies batch strides;
// kslab = z % zsplit splits K (partials at C + kslab*M*ldc; epilogue 0 only).
// epilogue: 0 = store, 1 = C += acc, 2 = softplus(acc+bias[n]), 3 = acc + bias[n]
__global__ __launch_bounds__(256) void gemm_bf16_k(
    const u16* __restrict__ A, int lda,
    const u16* __restrict__ W, int ldw,
    float* __restrict__ C, int ldc, int M, int Ncols, int K,
    const float* __restrict__ bias, int epilogue,
    int zsplit, size_t bsA, size_t bsW, size_t bsC, size_t bsBias)
{
  __shared__ __align__(16) u16 Asl[2][4096];
  __shared__ __align__(16) u16 Wsl[2][4096];
  const int tid = threadIdx.x;
  const int bm = blockIdx.y << 7, bn = blockIdx.x << 7;
  const int wv = tid >> 6, ln = tid & 63;
  const int wr = (wv >> 1) << 6, wc = (wv & 1) << 6;

  int kb = 0, ke = K;
  {
    int zb = (int)blockIdx.z;
    int dir = zb / zsplit, kslab = zb - dir*zsplit;
    A += (size_t)dir * bsA;
    W += (size_t)dir * bsW;
    C += (size_t)dir * bsC;
    if (bias) bias += (size_t)dir * bsBias;
    if (zsplit > 1) {
      int ksl = K / zsplit;
      kb = kslab * ksl; ke = kb + ksl;
      C += (size_t)kslab * (size_t)M * (size_t)ldc;
    }
  }

  const int q0 = (ln >> 4) * 8;
  const int r0 = wv*16 + (ln & 15);
  const int r1 = (wv+4)*16 + (ln & 15);

  int ar0 = bm + r0; if (ar0 >= M) ar0 = M-1;
  int ar1 = bm + r1; if (ar1 >= M) ar1 = M-1;
  int nr0 = bn + r0; if (nr0 >= Ncols) nr0 = Ncols-1;
  int nr1 = bn + r1; if (nr1 >= Ncols) nr1 = Ncols-1;
  const u16* A0 = A + (size_t)ar0*lda + q0;
  const u16* A1 = A + (size_t)ar1*lda + q0;
  const u16* W0 = W + (size_t)nr0*ldw + q0;
  const u16* W1 = W + (size_t)nr1*ldw + q0;

  auto STAGE = [&](int buf, int k0) {
    char* ab = (char*)&Asl[buf][0];
    char* wb = (char*)&Wsl[buf][0];
    glds16(A0 + k0, ab + wv*1024);
    glds16(A1 + k0, ab + 4096 + wv*1024);
    glds16(W0 + k0, wb + wv*1024);
    glds16(W1 + k0, wb + 4096 + wv*1024);
  };

  f32x4 acc[4][4];
  #pragma unroll
  for (int m = 0; m < 4; ++m)
    #pragma unroll
    for (int n = 0; n < 4; ++n) acc[m][n] = (f32x4){0.f,0.f,0.f,0.f};

  const int niter = (ke - kb) >> 5;
  STAGE(0, kb);
  for (int it = 0; it < niter; ++it) {
    const int p = it & 1;
    if (it + 1 < niter) {
      STAGE(p ^ 1, kb + (it + 1) * 32);
      asm volatile("s_waitcnt vmcnt(4)" ::: "memory");
    } else {
      asm volatile("s_waitcnt vmcnt(0)" ::: "memory");
    }
    __builtin_amdgcn_s_barrier();
    bf16x8 fa[4], fb[4];
    #pragma unroll
    for (int m = 0; m < 4; ++m)
      fa[m] = *reinterpret_cast<const bf16x8*>(&Asl[p][((wr>>4)+m)*512 + ln*8]);
    #pragma unroll
    for (int n = 0; n < 4; ++n)
      fb[n] = *reinterpret_cast<const bf16x8*>(&Wsl[p][((wc>>4)+n)*512 + ln*8]);
    #pragma unroll
    for (int m = 0; m < 4; ++m)
      #pragma unroll
      for (int n = 0; n < 4; ++n)
        acc[m][n] = __builtin_amdgcn_mfma_f32_16x16x32_bf16(fa[m], fb[n], acc[m][n], 0, 0, 0);
    __builtin_amdgcn_s_barrier();
  }

  const int crow0 = bm + wr + ((ln >> 4) << 2);
  const int ccol0 = bn + wc + (ln & 15);
  #pragma unroll
  for (int m = 0; m < 4; ++m) {
    #pragma unroll
    for (int q = 0; q < 4; ++q) {
      int row = crow0 + m*16 + q;
      if (row >= M) continue;
      float* Cr = C + (size_t)row*ldc;
      #pragma unroll
      for (int n = 0; n < 4; ++n) {
        int col = ccol0 + n*16;
        if (col >= Ncols) continue;
        float v = acc[m][n][q];
        if (epilogue == 1) v += Cr[col];
        else if (epilogue == 2) {
          v += bias[col];
          v = fmaxf(v, 0.f) + log1pf(__expf(-fabsf(v)));   // softplus
        } else if (epilogue == 3) v += bias[col];
        Cr[col] = v;
      }
    }
  }
}

// ---------------------------------------------------------------- reduce K-split slabs (both dirs) -> dbc f32 + dt bf16 (padded 64)
__global__ void reduce_split2_k(const float* __restrict__ part,
                                float* __restrict__ dbc2, u16* __restrict__ dt48,
                                int nsplit)
{
  int i = blockIdx.x * 256 + threadIdx.x;
  if (i >= 2*ROWS*DBCW) return;
  int dir = i / (ROWS*DBCW);
  int j   = i - dir*(ROWS*DBCW);
  const float* p = part + (size_t)dir*nsplit*(ROWS*DBCW);
  float s = 0.f;
  for (int z = 0; z < nsplit; ++z) s += p[(size_t)z*(ROWS*DBCW) + j];
  dbc2[i] = s;
  int row = j / DBCW, col = j - row*DBCW;
  if (col < RDIM)    dt48[(size_t)dir*ROWS*64 + (size_t)row*64 + col] = f2b(s);
  else if (col < 64) dt48[(size_t)dir*ROWS*64 + (size_t)row*64 + col] = 0;
}

// ---------------------------------------------------------------- fused: sum 4 out_proj K-slabs + residual add into h + next-layer LN -> bf16
__global__ __launch_bounds__(256) void reduce4_ln_k(
    const float* __restrict__ part, float* __restrict__ h,
    const float* __restrict__ w, const float* __restrict__ b,
    u16* __restrict__ y)
{
  int row = blockIdx.x;
  int t = threadIdx.x;
  const size_t S = (size_t)ROWS*DMODEL;
  const size_t base = (size_t)row*DMODEL;
  float v[3];
  #pragma unroll
  for (int j = 0; j < 3; ++j) {
    size_t idx = base + t + j*256;
    float s = (part[idx] + part[S+idx]) + (part[2*S+idx] + part[3*S+idx]);
    s += h[idx];
    h[idx] = s;
    v[j] = s;
  }
  if (!w) return;                 // last layer: no LN needed here
  float s = v[0]+v[1]+v[2], ss = v[0]*v[0]+v[1]*v[1]+v[2]*v[2];
  wave_reduce2(s, ss);
  __shared__ float sm[8];
  if ((t & 63) == 0) { sm[t>>6] = s; sm[4+(t>>6)] = ss; }
  __syncthreads();
  s = sm[0]+sm[1]+sm[2]+sm[3]; ss = sm[4]+sm[5]+sm[6]+sm[7];
  float mean = s*(1.f/768.f);
  float var  = ss*(1.f/768.f) - mean*mean;
  float rstd = rsqrtf(var + 1e-5f);
  u16* yr = y + base;
  #pragma unroll
  for (int j = 0; j < 3; ++j) {
    int col = t + j*256;
    yr[col] = f2b((v[j]-mean)*rstd*w[col] + b[col]);
  }
}

// ---------------------------------------------------------------- depthwise causal conv (K=4) + SiLU, both dirs, bf16 out
__global__ __launch_bounds__(256) void dwconv_silu_k(
    const float* __restrict__ xz,
    const float* __restrict__ w_f, const float* __restrict__ w_b,
    const float* __restrict__ b_f, const float* __restrict__ b_b,
    u16* __restrict__ outb2)
{
  const int dir = blockIdx.y;
  const float* w    = dir ? w_b : w_f;
  const float* bias = dir ? b_b : b_f;
  u16* outb = outb2 + (size_t)dir*RE;
  int idx = blockIdx.x * 256 + threadIdx.x;          // ROWS * EDIM/4
  int r = idx / (EDIM/4);
  int e4 = (idx - r*(EDIM/4)) * 4;
  int b = r / L_SEQ, t = r - b*L_SEQ;
  float4 acc = *reinterpret_cast<const float4*>(&bias[e4]);
  float4 wq0 = *reinterpret_cast<const float4*>(&w[(size_t)(e4+0)*4]);
  float4 wq1 = *reinterpret_cast<const float4*>(&w[(size_t)(e4+1)*4]);
  float4 wq2 = *reinterpret_cast<const float4*>(&w[(size_t)(e4+2)*4]);
  float4 wq3 = *reinterpret_cast<const float4*>(&w[(size_t)(e4+3)*4]);
  #pragma unroll
  for (int k = 0; k < 4; ++k) {
    int tt = t - 3 + k;
    if (tt >= 0) {
      int phys = dir ? (L_SEQ-1 - tt) : tt;
      float4 xv = *reinterpret_cast<const float4*>(
          &xz[((size_t)b*L_SEQ + phys)*XZDIM + e4]);
      float w0 = (k==0)?wq0.x:(k==1)?wq0.y:(k==2)?wq0.z:wq0.w;
      float w1 = (k==0)?wq1.x:(k==1)?wq1.y:(k==2)?wq1.z:wq1.w;
      float w2 = (k==0)?wq2.x:(k==1)?wq2.y:(k==2)?wq2.z:wq2.w;
      float w3 = (k==0)?wq3.x:(k==1)?wq3.y:(k==2)?wq3.z:wq3.w;
      acc.x = fmaf(xv.x, w0, acc.x);
      acc.y = fmaf(xv.y, w1, acc.y);
      acc.z = fmaf(xv.z, w2, acc.z);
      acc.w = fmaf(xv.w, w3, acc.w);
    }
  }
  float4 sv;
  sv.x = acc.x / (1.f + __expf(-acc.x));
  sv.y = acc.y / (1.f + __expf(-acc.y));
  sv.z = acc.z / (1.f + __expf(-acc.z));
  sv.w = acc.w / (1.f + __expf(-acc.w));
  ushort4 ob;
  ob.x = f2b(sv.x); ob.y = f2b(sv.y); ob.z = f2b(sv.z); ob.w = f2b(sv.w);
  *reinterpret_cast<ushort4*>(&outb[(size_t)r*EDIM + e4]) = ob;
}

// ---------------------------------------------------------------- SSM scan (both dirs, chunked LDS, packed-du, DPP reduce)
// yb[s][g] already includes the D-term (yp + u*D) -- writeout only gates with silu(z).
__device__ __forceinline__ float dpp_reduce16(float v) {
  v += __int_as_float(__builtin_amdgcn_update_dpp(0, __float_as_int(v), 0x111, 0xf, 0xf, true));
  v += __int_as_float(__builtin_amdgcn_update_dpp(0, __float_as_int(v), 0x112, 0xf, 0xf, true));
  v += __int_as_float(__builtin_amdgcn_update_dpp(0, __float_as_int(v), 0x114, 0xf, 0xf, true));
  v += __int_as_float(__builtin_amdgcn_update_dpp(0, __float_as_int(v), 0x118, 0xf, 0xf, true));
  return v;   // lane 15 of each 16-lane row holds the sum
}

#define TC 32
#define NCH ((L_SEQ + TC - 1) / TC)   /* 17 */

__global__ __launch_bounds__(256) void ssm_scan_k(
    const float* __restrict__ delta2, const u16* __restrict__ ub2,
    const float* __restrict__ dbc2,
    const float* __restrict__ Alf, const float* __restrict__ Alb,
    const float* __restrict__ Dpf, const float* __restrict__ Dpb,
    const float* __restrict__ xz,  u16* __restrict__ yhalf)
{
  __shared__ __align__(16) float du[2][TC][16][2];   // [d,u] interleaved -> 1 b64 read/step
  __shared__ __align__(16) float Bs[2][16][TC+4];
  __shared__ __align__(16) float Cs[2][16][TC+4];
  __shared__ __align__(16) float yb[TC][16];

  const int dir = blockIdx.z;
  const float* delta = delta2 + (size_t)dir*RE;
  const u16*   ub    = ub2    + (size_t)dir*RE;
  const float* dbc   = dbc2   + (size_t)dir*ROWS*DBCW;
  const float* A_log = dir ? Alb : Alf;
  const float* Dp    = dir ? Dpb : Dpf;
  u16* yh = yhalf + (size_t)dir*RE;

  const int tid = threadIdx.x;
  const int g = tid >> 4, n = tid & 15;
  const int b = blockIdx.y;
  const int e0 = blockIdx.x * 16;
  const int e = e0 + g;
  const size_t rb = (size_t)b * L_SEQ;

  const float a  = -__expf(A_log[(size_t)e*NSTATE + n]);
  const float dp = Dp[e];

  const int ss_ = tid >> 3;          // 0..31 : step within chunk
  const int c2  = (tid & 7) * 2;     // 0..14 : e-pair
  const int j4  = (tid & 7) * 4;     // 0..28 : quad within 32 B/C floats

  float2 dv = make_float2(0,0);
  uint32_t uv = 0;
  float4 bcv = make_float4(0,0,0,0);

  auto LOAD = [&](int c) {
    int Tn = min(TC, L_SEQ - c*TC);
    if (ss_ < Tn) {
      size_t r = rb + c*TC + ss_;
      dv  = *reinterpret_cast<const float2*>(&delta[r*EDIM + e0 + c2]);
      uv  = *reinterpret_cast<const uint32_t*>(&ub[r*EDIM + e0 + c2]);
      bcv = *reinterpret_cast<const float4*>(&dbc[r*DBCW + RDIM + j4]);
    }
  };
  auto STORE = [&](int p, int c) {
    int Tn = min(TC, L_SEQ - c*TC);
    if (ss_ < Tn) {
      float2 w0 = make_float2(dv.x, __uint_as_float((uv & 0xffffu) << 16));
      float2 w1 = make_float2(dv.y, __uint_as_float(uv & 0xffff0000u));
      *reinterpret_cast<float2*>(&du[p][ss_][c2][0])   = w0;
      *reinterpret_cast<float2*>(&du[p][ss_][c2+1][0]) = w1;
      if (j4 < 16) {
        Bs[p][j4  ][ss_] = bcv.x; Bs[p][j4+1][ss_] = bcv.y;
        Bs[p][j4+2][ss_] = bcv.z; Bs[p][j4+3][ss_] = bcv.w;
      } else {
        Cs[p][j4-16][ss_] = bcv.x; Cs[p][j4-15][ss_] = bcv.y;
        Cs[p][j4-14][ss_] = bcv.z; Cs[p][j4-13][ss_] = bcv.w;
      }
    }
  };

  float hst = 0.f;
  LOAD(0);
  STORE(0, 0);
  __syncthreads();

  int p = 0;
  for (int c = 0; c < NCH; ++c) {
    const int t0 = c * TC;
    const int T  = min(TC, L_SEQ - t0);
    if (c + 1 < NCH) LOAD(c + 1);

    int s = 0;
    for (; s + 3 < T; s += 4) {
      float4 Bv = *reinterpret_cast<const float4*>(&Bs[p][n][s]);
      float4 Cv = *reinterpret_cast<const float4*>(&Cs[p][n][s]);
      #pragma unroll
      for (int i = 0; i < 4; ++i) {
        float Bt = (i==0)?Bv.x:(i==1)?Bv.y:(i==2)?Bv.z:Bv.w;
        float Ct = (i==0)?Cv.x:(i==1)?Cv.y:(i==2)?Cv.z:Cv.w;
        float2 duv = *reinterpret_cast<const float2*>(&du[p][s+i][g][0]);
        float d  = duv.x;
        float uu = duv.y;
        hst = fmaf(hst, __expf(d*a), d*uu*Bt);
        float yp = dpp_reduce16(hst * Ct);
        if (n == 15) yb[s+i][g] = yp + uu*dp;
      }
    }
    for (; s < T; ++s) {
      float Bt = Bs[p][n][s], Ct = Cs[p][n][s];
      float2 duv = *reinterpret_cast<const float2*>(&du[p][s][g][0]);
      float d  = duv.x;
      float uu = duv.y;
      hst = fmaf(hst, __expf(d*a), d*uu*Bt);
      float yp = dpp_reduce16(hst * Ct);
      if (n == 15) yb[s][g] = yp + uu*dp;
    }
    __syncthreads();

    // writeout: yb already includes D-term; just gate with silu(z) and store bf16
    if (ss_ < T) {
      int t = t0 + ss_;
      int phys = dir ? (L_SEQ-1 - t) : t;
      size_t pr = rb + phys;
      float2 yv = *reinterpret_cast<const float2*>(&yb[ss_][c2]);
      float2 zv = *reinterpret_cast<const float2*>(&xz[pr*XZDIM + EDIM + e0 + c2]);
      ushort2 o;
      o.x = f2b(yv.x * (zv.x / (1.f + __expf(-zv.x))));
      o.y = f2b(yv.y * (zv.y / (1.f + __expf(-zv.y))));
      *reinterpret_cast<ushort2*>(&yh[pr*EDIM + e0 + c2]) = o;
    }
    if (c + 1 < NCH) STORE(p ^ 1, c + 1);
    __syncthreads();
    p ^= 1;
  }
}

// ---------------------------------------------------------------- yf + yb -> bf16 (8-wide)
__global__ __launch_bounds__(256) void add_ybf_k(const u16* __restrict__ yhalf,
                                                 u16* __restrict__ ybf)
{
  size_t i = ((size_t)blockIdx.x*256 + threadIdx.x) * 8;
  uint4 a = *reinterpret_cast<const uint4*>(yhalf + i);
  uint4 b = *reinterpret_cast<const uint4*>(yhalf + RE + i);
  uint32_t av[4] = {a.x, a.y, a.z, a.w};
  uint32_t bv[4] = {b.x, b.y, b.z, b.w};
  uint32_t ov[4];
  #pragma unroll
  for (int q = 0; q < 4; ++q) {
    float lo = __uint_as_float((av[q] & 0xffffu) << 16) +
               __uint_as_float((bv[q] & 0xffffu) << 16);
    float hi = __uint_as_float(av[q] & 0xffff0000u) +
               __uint_as_float(bv[q] & 0xffff0000u);
    ov[q] = (uint32_t)f2b(lo) | ((uint32_t)f2b(hi) << 16);
  }
  uint4 o = {ov[0], ov[1], ov[2], ov[3]};
  *reinterpret_cast<uint4*>(ybf + i) = o;
}

// ---------------------------------------------------------------- head
__global__ __launch_bounds__(256) void head_k(
    const float* __restrict__ h,
    const float* __restrict__ fnw, const float* __restrict__ fnb,
    const float* __restrict__ hnw, const float* __restrict__ hnb,
    const float* __restrict__ hw,  const float* __restrict__ hb,
    float* __restrict__ out)
{
  int b = blockIdx.x, t = threadIdx.x;
  const float* xr = h + ((size_t)b*L_SEQ + 256)*DMODEL;
  __shared__ float feat[DMODEL];
  __shared__ float sm[8];
  float v0 = xr[t], v1 = xr[t+256], v2 = xr[t+512];
  float s = v0+v1+v2, ss = v0*v0+v1*v1+v2*v2;
  wave_reduce2(s, ss);
  if ((t & 63) == 0) { sm[t>>6] = s; sm[4+(t>>6)] = ss; }
  __syncthreads();
  s = sm[0]+sm[1]+sm[2]+sm[3]; ss = sm[4]+sm[5]+sm[6]+sm[7];
  float mean = s*(1.f/768.f), var = ss*(1.f/768.f) - mean*mean;
  float rstd = rsqrtf(var + 1e-5f);
  float f0 = (v0-mean)*rstd*fnw[t]     + fnb[t];
  float f1 = (v1-mean)*rstd*fnw[t+256] + fnb[t+256];
  float f2 = (v2-mean)*rstd*fnw[t+512] + fnb[t+512];
  s = f0+f1+f2; ss = f0*f0+f1*f1+f2*f2;
  wave_reduce2(s, ss);
  __syncthreads();
  if ((t & 63) == 0) { sm[t>>6] = s; sm[4+(t>>6)] = ss; }
  __syncthreads();
  s = sm[0]+sm[1]+sm[2]+sm[3]; ss = sm[4]+sm[5]+sm[6]+sm[7];
  mean = s*(1.f/768.f); var = ss*(1.f/768.f) - mean*mean;
  rstd = rsqrtf(var + 1e-5f);
  feat[t]     = (f0-mean)*rstd*hnw[t]     + hnb[t];
  feat[t+256] = (f1-mean)*rstd*hnw[t+256] + hnb[t+256];
  feat[t+512] = (f2-mean)*rstd*hnw[t+512] + hnb[t+512];
  __syncthreads();
  for (int c = 0; c < 10; ++c) {
    float d = 0.f;
    for (int i = t; i < DMODEL; i += 256) d = fmaf(feat[i], hw[(size_t)c*DMODEL + i], d);
    #pragma unroll
    for (int o = 32; o; o >>= 1) d += __shfl_down(d, o);
    __syncthreads();
    if ((t & 63) == 0) sm[t>>6] = d;
    __syncthreads();
    if (t == 0) out[b*10 + c] = sm[0]+sm[1]+sm[2]+sm[3] + hb[c];
  }
}

// ================================================================ launch
extern "C" void kernel_launch(void* const* d_in, const int* in_sizes, int n_in,
                              void* d_out, int out_size, void* d_ws, size_t ws_size,
                              hipStream_t stream)
{
  (void)in_sizes; (void)n_in; (void)out_size; (void)ws_size;
  const float* x           = (const float*)d_in[0];
  const float* patch_w     = (const float*)d_in[1];
  const float* patch_b     = (const float*)d_in[2];
  const float* cls_tok     = (const float*)d_in[3];
  const float* norm_w      = (const float*)d_in[4];
  const float* norm_b      = (const float*)d_in[5];
  const float* in_proj_w   = (const float*)d_in[6];
  const float* conv_w_f    = (const float*)d_in[7];
  const float* conv_b_f    = (const float*)d_in[8];
  const float* x_proj_w_f  = (const float*)d_in[9];
  const float* dt_proj_w_f = (const float*)d_in[10];
  const float* dt_proj_b_f = (const float*)d_in[11];
  const float* A_log_f     = (const float*)d_in[12];
  const float* D_f         = (const float*)d_in[13];
  const float* conv_w_b    = (const float*)d_in[14];
  const float* conv_b_b    = (const float*)d_in[15];
  const float* x_proj_w_b  = (const float*)d_in[16];
  const float* dt_proj_w_b = (const float*)d_in[17];
  const float* dt_proj_b_b = (const float*)d_in[18];
  const float* A_log_b     = (const float*)d_in[19];
  const float* D_b         = (const float*)d_in[20];
  const float* out_proj_w  = (const float*)d_in[21];
  const float* fnorm_w     = (const float*)d_in[22];
  const float* fnorm_b     = (const float*)d_in[23];
  const float* head_norm_w = (const float*)d_in[24];
  const float* head_norm_b = (const float*)d_in[25];
  const float* head_w      = (const float*)d_in[26];
  const float* head_b      = (const float*)d_in[27];
  float* out = (float*)d_out;

  // workspace layout (float units) — base ~172 MB
  float* ws = (float*)d_ws;
  float* h      = ws;        ws += (size_t)ROWS*DMODEL;
  u16*   hn     = (u16*)ws;  ws += RE/2;                  // [ROWS][1536] bf16 region
  u16*   ybf    = hn;                                     // alias: hn consumed by in_proj before add_ybf writes
  float* xz     = ws;        ws += (size_t)ROWS*XZDIM;
  u16*   ubufb2 = (u16*)ws;  ws += RE;                    // [2][ROWS][EDIM] bf16
  float* dbc2   = ws;        ws += (size_t)2*ROWS*DBCW;
  u16*   dt48b2 = (u16*)ws;  ws += (size_t)2*ROWS*64/2;
  float* delta2 = ws;        ws += 2*RE;                  // [2][ROWS][EDIM] f32
  u16*   yhalf  = (u16*)ws;  ws += RE;                    // [2][ROWS][EDIM] bf16
  u16*   wbf_a  = (u16*)ws;  ws += (size_t)XZDIM*DMODEL/2;
  u16*   wbf_b  = (u16*)ws;  ws += (size_t)DMODEL*EDIM/2;
  u16*   pwbf   = (u16*)ws;  ws += (size_t)DMODEL*256/2;
  u16*   xwbf   = (u16*)ws;  ws += (size_t)2*12*DBCW*EDIM/2;  // [2][12][80][1536]
  u16*   dtwbf  = (u16*)ws;  ws += (size_t)2*12*EDIM*64/2;    // [2][12][1536][64]
  float* dtb2   = ws;        ws += (size_t)2*12*EDIM;
  float* dbcp   = delta2;          // x_proj partials alias (21 MB <= 50 MB, pre-dt_proj)
  float* opart  = delta2;          // out_proj partials alias (4 slabs x 12.6 MB = 50.4 MB, post-scan)
  u16*   Pim    = ubufb2;          // patch-phase alias
  float* tokf   = delta2;          // patch-phase alias

  // ---- one-time weight conversions
  f2b_k<<<(DMODEL*256)/1024, 256, 0, stream>>>(patch_w, pwbf, DMODEL*256);
  f2b_k<<<(12*DBCW*EDIM)/1024, 256, 0, stream>>>(x_proj_w_f, xwbf, 12*DBCW*EDIM);
  f2b_k<<<(12*DBCW*EDIM)/1024, 256, 0, stream>>>(x_proj_w_b, xwbf + (size_t)12*DBCW*EDIM, 12*DBCW*EDIM);
  cvt_dtw_k<<<(12*EDIM*16)/256, 256, 0, stream>>>(dt_proj_w_f, dtwbf, 12*EDIM);
  cvt_dtw_k<<<(12*EDIM*16)/256, 256, 0, stream>>>(dt_proj_w_b, dtwbf + (size_t)12*EDIM*64, 12*EDIM);
  hipMemcpyAsync(dtb2,           dt_proj_b_f, (size_t)12*EDIM*4, hipMemcpyDeviceToDevice, stream);
  hipMemcpyAsync(dtb2 + 12*EDIM, dt_proj_b_b, (size_t)12*EDIM*4, hipMemcpyDeviceToDevice, stream);

  // ---- patch embed as GEMM
  im2col_k<<<(4096*64)/256, 256, 0, stream>>>(x, Pim);
  {
    dim3 g(DMODEL/128, 4096/128);
    gemm_bf16_k<<<g, 256, 0, stream>>>(Pim, 256, pwbf, 256, tokf, DMODEL,
                                       4096, DMODEL, 256, patch_b, 3,
                                       1, 0, 0, 0, 0);
  }
  insert_k<<<(ROWS*192 + 255)/256, 256, 0, stream>>>(tokf, cls_tok, h);

  const int MT = (ROWS + 127)/128;   // 33

  // layer-0 LN (subsequent LNs fused into reduce4_ln_k)
  layernorm_k<<<ROWS, 256, 0, stream>>>(h, norm_w, norm_b, hn);

  for (int i = 0; i < 12; ++i) {
    f2b2_k<<<(XZDIM*DMODEL + DMODEL*EDIM)/1024, 256, 0, stream>>>(
        in_proj_w + (size_t)i*XZDIM*DMODEL, out_proj_w + (size_t)i*DMODEL*EDIM,
        wbf_a, wbf_b, XZDIM*DMODEL, DMODEL*EDIM);
    {   // in_proj (bf16 MFMA)
      dim3 g(XZDIM/128, MT);
      gemm_bf16_k<<<g, 256, 0, stream>>>(hn, DMODEL, wbf_a, DMODEL,
                                         xz, XZDIM, ROWS, XZDIM, DMODEL, nullptr, 0,
                                         1, 0, 0, 0, 0);
    }
    {   // dwconv both dirs
      dim3 g((ROWS*EDIM/4)/256, 2);
      dwconv_silu_k<<<g, 256, 0, stream>>>(xz,
          conv_w_f + (size_t)i*EDIM*4, conv_w_b + (size_t)i*EDIM*4,
          conv_b_f + (size_t)i*EDIM,   conv_b_b + (size_t)i*EDIM, ubufb2);
    }
    {   // x_proj both dirs (K-split 8 each)
      dim3 g(1, MT, 2*KSPLIT_DBC);
      gemm_bf16_k<<<g, 256, 0, stream>>>(ubufb2, EDIM,
          xwbf + (size_t)i*DBCW*EDIM, EDIM,
          dbcp, DBCW, ROWS, DBCW, EDIM, nullptr, 0,
          KSPLIT_DBC, RE, (size_t)12*DBCW*EDIM, (size_t)KSPLIT_DBC*ROWS*DBCW, 0);
      reduce_split2_k<<<(2*ROWS*DBCW + 255)/256, 256, 0, stream>>>(
          dbcp, dbc2, dt48b2, KSPLIT_DBC);
    }
    {   // dt_proj both dirs (K padded 48->64) + bias + softplus
      dim3 g(EDIM/128, MT, 2);
      gemm_bf16_k<<<g, 256, 0, stream>>>(dt48b2, 64,
          dtwbf + (size_t)i*EDIM*64, 64,
          delta2, EDIM, ROWS, EDIM, 64, dtb2 + (size_t)i*EDIM, 2,
          1, (size_t)ROWS*64, (size_t)12*EDIM*64, RE, (size_t)12*EDIM);
    }
    {   // scan both dirs
      dim3 g(EDIM/16, NB, 2);
      ssm_scan_k<<<g, 256, 0, stream>>>(delta2, ubufb2, dbc2,
          A_log_f + (size_t)i*EDIM*NSTATE, A_log_b + (size_t)i*EDIM*NSTATE,
          D_f + (size_t)i*EDIM, D_b + (size_t)i*EDIM, xz, yhalf);
    }
    add_ybf_k<<<(int)(RE/8/256), 256, 0, stream>>>(yhalf, ybf);
    {   // out_proj (bf16 MFMA, K-split 4 into opart)
      dim3 g(DMODEL/128, MT, 4);
      gemm_bf16_k<<<g, 256, 0, stream>>>(ybf, EDIM, wbf_b, EDIM,
                                         opart, DMODEL, ROWS, DMODEL, EDIM, nullptr, 0,
                                         4, 0, 0, 0, 0);
    }
    {   // fused: sum 4 slabs + residual into h + next-layer LN -> hn
      const float* lw = (i < 11) ? (norm_w + (size_t)(i+1)*DMODEL) : nullptr;
      const float* lb = (i < 11) ? (norm_b + (size_t)(i+1)*DMODEL) : nullptr;
      reduce4_ln_k<<<ROWS, 256, 0, stream>>>(opart, h, lw, lb, hn);
    }
  }

  head_k<<<NB, 256, 0, stream>>>(h, fnorm_w, fnorm_b, head_norm_w, head_norm_b,
                                 head_w, head_b, out);
}